// Round 5
// baseline (32.777 us; speedup 1.0000x reference)
//
#include <hip/hip_runtime.h>
#include <math.h>

// Second-order cone projection over 3 fixed groups:
//   (d=4,  m=2,000,000)  floats [0, 8M)
//   (d=8,  m=1,000,000)  floats [8M, 16M)
//   (d=16, m=  500,000)  floats [16M, 24M)
// Per row [t, z...]: nz = max(||z||, 1e-12)
//   nz <= t+eps -> identity ; nz <= -t -> zero ; else 0.5*(1+t/nz)*[nz, z...]
//
// R1 thread-per-row: 35.3 us. R3 NT stores: regressed (write amplification),
// reverted. R4 thread-per-quad + shfl reduce: 32.7 us (93% of copy ceiling).
// R5: 2 quads per thread (offset by blockDim -> both accesses stay
// lane-contiguous) for ILP / latency hiding; grid halved.

#define SOC_EPS 1e-12f

typedef float floatx4 __attribute__((ext_vector_type(4)));

template<int QPR>  // quads per row: 1 (d=4), 2 (d=8), 4 (d=16)
__device__ __forceinline__ void proj_quad(const floatx4* __restrict__ ip,
                                          floatx4* __restrict__ op,
                                          long long q, long long nq) {
    if (q >= nq) return;
    floatx4 v = ip[q];                 // lane-contiguous
    int sub = (int)(q & (QPR - 1));

    float ssq = fmaf(v.y, v.y, fmaf(v.z, v.z, v.w * v.w));
    if (QPR > 1 && sub != 0) ssq = fmaf(v.x, v.x, ssq);

    float tot = ssq;
    if (QPR >= 2) tot += __shfl_xor(tot, 1);
    if (QPR >= 4) tot += __shfl_xor(tot, 2);

    float t;
    if (QPR == 1) t = v.x;
    else          t = __shfl(v.x, ((int)(threadIdx.x & 63)) & ~(QPR - 1));

    float nz = fmaxf(sqrtf(tot), SOC_EPS);
    bool cone  = (nz <= t + SOC_EPS);
    bool polar = (nz <= -t);
    float c = 0.5f * (1.0f + t / nz);

    float px = (QPR == 1 || sub == 0) ? nz : v.x;

    floatx4 o;
    o.x = cone ? v.x : (polar ? 0.0f : c * px);
    o.y = cone ? v.y : (polar ? 0.0f : c * v.y);
    o.z = cone ? v.z : (polar ? 0.0f : c * v.z);
    o.w = cone ? v.w : (polar ? 0.0f : c * v.w);
    op[q] = o;
}

template<int QPR>
__device__ __forceinline__ void proj_block(const float* __restrict__ in,
                                           float* __restrict__ out,
                                           int rel_b, long long nq) {
    const floatx4* ip = reinterpret_cast<const floatx4*>(in);
    floatx4* op = reinterpret_cast<floatx4*>(out);
    long long base = (long long)rel_b * (2 * blockDim.x) + threadIdx.x;
    // two quads per thread, second offset by blockDim (stays lane-contiguous;
    // 256 % QPR == 0 so row lane-groups remain aligned)
    proj_quad<QPR>(ip, op, base, nq);
    proj_quad<QPR>(ip, op, base + blockDim.x, nq);
}

__global__ __launch_bounds__(256)
void SecondOrderConeProjector_kernel(const float* __restrict__ x,
                                     float* __restrict__ out,
                                     int nb0, int nb1,
                                     long long nq0, long long nq1, long long nq2,
                                     long long off1, long long off2) {
    int b = blockIdx.x;
    if (b < nb0) {
        proj_block<1>(x, out, b, nq0);
    } else if (b < nb0 + nb1) {
        proj_block<2>(x + off1, out + off1, b - nb0, nq1);
    } else {
        proj_block<4>(x + off2, out + off2, b - nb0 - nb1, nq2);
    }
}

extern "C" void kernel_launch(void* const* d_in, const int* in_sizes, int n_in,
                              void* d_out, int out_size, void* d_ws, size_t ws_size,
                              hipStream_t stream) {
    const float* x = (const float*)d_in[0];
    float* out = (float*)d_out;

    const long long m0 = 2000000, m1 = 1000000, m2 = 500000;
    const long long off1 = 4 * m0;            // 8,000,000 floats
    const long long off2 = off1 + 8 * m1;     // 16,000,000 floats

    const long long nq0 = m0;                 // 2,000,000 quads (d=4)
    const long long nq1 = 2 * m1;             // 2,000,000 quads (d=8)
    const long long nq2 = 4 * m2;             // 2,000,000 quads (d=16)

    const int block = 256;
    const int qpb = 2 * block;                // 2 quads per thread
    const int nb0 = (int)((nq0 + qpb - 1) / qpb);  // 3907
    const int nb1 = (int)((nq1 + qpb - 1) / qpb);  // 3907
    const int nb2 = (int)((nq2 + qpb - 1) / qpb);  // 3907
    const int grid = nb0 + nb1 + nb2;

    SecondOrderConeProjector_kernel<<<grid, block, 0, stream>>>(
        x, out, nb0, nb1, nq0, nq1, nq2, off1, off2);
}